// Round 1
// baseline (154.067 us; speedup 1.0000x reference)
//
#include <hip/hip_runtime.h>

typedef __attribute__((ext_vector_type(8))) __bf16 bf16x8;
typedef __attribute__((ext_vector_type(8))) unsigned short us8;
typedef __attribute__((ext_vector_type(4))) float f32x4;

#define NB 16
#define B_TOTAL 131072

__device__ __forceinline__ unsigned short f2bf(float f) {
  union { float f; unsigned int u; } c; c.f = f;
  unsigned int u = c.u;
  u += 0x7fffu + ((u >> 16) & 1u);   // RNE
  return (unsigned short)(u >> 16);
}
__device__ __forceinline__ float bf2f(unsigned short s) {
  union { unsigned int u; float f; } c; c.u = ((unsigned int)s) << 16;
  return c.f;
}
__device__ __forceinline__ bf16x8 as_bf(us8 v) {
  union { us8 u; bf16x8 b; } c; c.u = v; return c.b;
}
__device__ __forceinline__ float fast_tanh(float x) {
  float t = __expf(2.0f * x);        // v_exp_f32; inf-safe: 1-2/(inf)=1, 1-2/(0+1)=-1
  return 1.0f - 2.0f / (t + 1.0f);
}

// ---------------- prep: pre-arrange B-fragments (bf16) into ws -----------------
// rwfrag[s][kh][lane][e] = rw[h=(lane>>4)*8+e][k=kh*16+(lane&15)][s]
// qwfrag[s][kh][lane<16][e] = qw[i=e][h=kh*16+lane][s]
// dgfrag[kh][lane][e] = (h==k) ? bf16(1 - 0.1/tau[k]) : 0
__global__ void shq_prep(const float* __restrict__ qw, const float* __restrict__ rw,
                         const float* __restrict__ tau,
                         unsigned short* __restrict__ rwfrag,
                         unsigned short* __restrict__ qwfrag,
                         unsigned short* __restrict__ dgfrag) {
  int g = blockIdx.x * 256 + threadIdx.x;
  if (g < 2048) {                       // 16 s * 2 kh * 64 lanes
    int s = g >> 7, kh = (g >> 6) & 1, ln = g & 63;
    int k = kh * 16 + (ln & 15), h0 = (ln >> 4) * 8;
    us8 v;
#pragma unroll
    for (int e = 0; e < 8; ++e) v[e] = f2bf(rw[((h0 + e) * 32 + k) * 16 + s]);
    *(us8*)(rwfrag + g * 8) = v;
  } else if (g < 2560) {                // 16 s * 2 kh * 16 lanes
    int j = g - 2048;
    int s = j >> 5, kh = (j >> 4) & 1, ln = j & 15;
    int hc = kh * 16 + ln;
    us8 v;
#pragma unroll
    for (int e = 0; e < 8; ++e) v[e] = f2bf(qw[(e * 32 + hc) * 16 + s]);
    *(us8*)(qwfrag + j * 8) = v;
  } else if (g < 2688) {                // 2 kh * 64 lanes
    int j = g - 2560;
    int kh = (j >> 6) & 1, ln = j & 63;
    int k = kh * 16 + (ln & 15), h0 = (ln >> 4) * 8;
    unsigned short ab = f2bf(1.0f - 0.1f / tau[k]);
    us8 v;
#pragma unroll
    for (int e = 0; e < 8; ++e) v[e] = (h0 + e == k) ? ab : (unsigned short)0;
    *(us8*)(dgfrag + j * 8) = v;
  }
}

// ---------------- main kernel: 512 threads = 16 batch rows ----------------
__global__ __launch_bounds__(512, 4) void shq_main(
    const float* __restrict__ x, const float* __restrict__ hq_g,
    const float* __restrict__ syn, const float* __restrict__ corr,
    const unsigned short* __restrict__ rwfrag,
    const unsigned short* __restrict__ qwfrag,
    const unsigned short* __restrict__ dgfrag,
    float* __restrict__ out) {
  // lds_a: phase1/2 = hqT[s][b][h] bf16 (stride s:640, b:40); phase3 = stable[b][s][h] (stride b:648, s:40)
  __shared__ unsigned short lds_a[10368];
  __shared__ unsigned short lds_nq[10368];  // nqT[b][s][h] bf16, stride b:648, s:40
  __shared__ float lds_pi[NB * 16 * 2];     // (prob, inv_norm) per (b,s)

  const int tid = threadIdx.x;
  const int b0 = blockIdx.x * NB;
  const int lane = tid & 63;
  const int w = tid >> 6;     // wave id: owns s = 2w, 2w+1

  // ---- prologue: issue phase-2 operand loads early (L2-resident ws) ----
  us8 z8 = {0, 0, 0, 0, 0, 0, 0, 0};
  us8 rwf_[2][2], qwf_[2][2], dg_[2];
#pragma unroll
  for (int sl = 0; sl < 2; ++sl) {
#pragma unroll
    for (int kh = 0; kh < 2; ++kh) {
      int s = 2 * w + sl;
      rwf_[sl][kh] = *(const us8*)(rwfrag + ((s * 2 + kh) * 64 + lane) * 8);
      qwf_[sl][kh] = (lane < 16) ? *(const us8*)(qwfrag + ((s * 2 + kh) * 16 + lane) * 8) : z8;
    }
  }
  dg_[0] = *(const us8*)(dgfrag + lane * 8);
  dg_[1] = *(const us8*)(dgfrag + (64 + lane) * 8);
  us8 xu = z8;
  if (lane < 16) {
    const float* xb = x + (size_t)(b0 + lane) * 8;
    f32x4 a = *(const f32x4*)xb, b = *(const f32x4*)(xb + 4);
    xu[0] = f2bf(a[0]); xu[1] = f2bf(a[1]); xu[2] = f2bf(a[2]); xu[3] = f2bf(a[3]);
    xu[4] = f2bf(b[0]); xu[5] = f2bf(b[1]); xu[6] = f2bf(b[2]); xu[7] = f2bf(b[3]);
  }

  // ---- phase 1: thread=(bl,h): syndrome -> mask -> correction -> hqT to LDS ----
  {
    const int bl = tid >> 5, hh = tid & 31;
    const float* hb = hq_g + (((size_t)(b0 + bl) * 32) + hh) * 16;
    f32x4 h0 = *(const f32x4*)(hb), h1 = *(const f32x4*)(hb + 4);
    f32x4 h2 = *(const f32x4*)(hb + 8), h3 = *(const f32x4*)(hb + 12);
    float hrow[16];
#pragma unroll
    for (int q = 0; q < 4; ++q) {
      hrow[0 + q] = h0[q]; hrow[4 + q] = h1[q]; hrow[8 + q] = h2[q]; hrow[12 + q] = h3[q];
    }
    float sd[4];
#pragma unroll
    for (int c = 0; c < 4; ++c) {
      float a = 0.f;
#pragma unroll
      for (int s = 0; s < 16; ++s) a = fmaf(hrow[s], syn[c * 16 + s], a);
      sd[c] = (fabsf(a) > 0.01f) ? a : 0.f;
    }
#pragma unroll
    for (int s = 0; s < 16; ++s) {
      float cs = sd[0] * corr[s] + sd[1] * corr[16 + s] + sd[2] * corr[32 + s] + sd[3] * corr[48 + s];
      lds_a[s * 640 + bl * 40 + hh] = f2bf(hrow[s] - cs);
    }
  }
  __syncthreads();

  // ---- phase 2: MFMA rec+inp+decay per (s, khalf); write new_q to LDS ----
  {
    f32x4 zro = {0.f, 0.f, 0.f, 0.f};
#pragma unroll
    for (int sl = 0; sl < 2; ++sl) {
      int s = 2 * w + sl;
      us8 hq_u = *(const us8*)&lds_a[s * 640 + (lane & 15) * 40 + (lane >> 4) * 8];
      bf16x8 hqf = as_bf(hq_u);
#pragma unroll
      for (int kh = 0; kh < 2; ++kh) {
        f32x4 acc = __builtin_amdgcn_mfma_f32_16x16x32_bf16(as_bf(xu), as_bf(qwf_[sl][kh]), zro, 0, 0, 0);
        acc = __builtin_amdgcn_mfma_f32_16x16x32_bf16(hqf, as_bf(rwf_[sl][kh]), acc, 0, 0, 0);
        f32x4 na;
#pragma unroll
        for (int r = 0; r < 4; ++r) na[r] = 0.1f * fast_tanh(acc[r]);
        na = __builtin_amdgcn_mfma_f32_16x16x32_bf16(hqf, as_bf(dg_[kh]), na, 0, 0, 0);
#pragma unroll
        for (int r = 0; r < 4; ++r) {
          int br = (lane >> 4) * 4 + r;
          int k = kh * 16 + (lane & 15);
          lds_nq[br * 648 + s * 40 + k] = f2bf(na[r]);
        }
      }
    }
  }
  __syncthreads();

  // ---- phase 3a: thread=(b,s): coupling -> stable -> norm/probs ----
  if (tid < 256) {
    int b3 = tid >> 4, s3 = tid & 15;
    int base = b3 * 648 + s3 * 40;
    us8 r0[4], rm[4], rp[4];
#pragma unroll
    for (int q = 0; q < 4; ++q) {
      r0[q] = *(const us8*)&lds_nq[base + q * 8];
      rm[q] = (s3 > 0) ? *(const us8*)&lds_nq[base - 40 + q * 8] : z8;
      rp[q] = (s3 < 15) ? *(const us8*)&lds_nq[base + 40 + q * 8] : z8;
    }
    float ssq = 0.f, sab = 0.f;
#pragma unroll
    for (int q = 0; q < 4; ++q) {
      us8 stq;
#pragma unroll
      for (int e = 0; e < 8; ++e) {
        float n0 = bf2f(r0[q][e]);
        float ent = 0.4f * n0 * bf2f(rp[q][e]) + 0.4f * bf2f(rm[q][e]) * n0;
        float st = fmaf(0.1f, ent, n0);
        ssq = fmaf(st, st, ssq);
        sab += fabsf(st);
        stq[e] = f2bf(st);
      }
      *(us8*)&lds_a[base + q * 8] = stq;   // stable, [b][s][h] stride 648/40
    }
    float norm = sqrtf(ssq);
    float inv = 1.0f / (norm + 1e-8f);
    float energy = ssq * inv * inv;
    float mag = sab * inv;
    float pu = mag / (energy + 1e-6f);
    float psum = pu;
#pragma unroll
    for (int m = 1; m < 16; m <<= 1) psum += __shfl_xor(psum, m, 16);
    lds_pi[(b3 * 16 + s3) * 2 + 0] = pu / psum;
    lds_pi[(b3 * 16 + s3) * 2 + 1] = inv;
  }
  __syncthreads();

  // ---- phase 3b: thread=(b,h): q_norm + output, coalesced stores ----
  {
    const int b3 = tid >> 5, h3 = tid & 31;
    float oacc = 0.f;
    float qn[16];
#pragma unroll
    for (int s = 0; s < 16; ++s) {
      float st = bf2f(lds_a[b3 * 648 + s * 40 + h3]);
      float2 pi = *(const float2*)&lds_pi[(b3 * 16 + s) * 2];
      float q = st * pi.y;
      qn[s] = q;
      oacc = fmaf(q, pi.x, oacc);
    }
    out[(size_t)(b0 + b3) * 32 + h3] = oacc;
    float* qp = out + 4194304 + (((size_t)(b0 + b3) * 32) + h3) * 16;
    f32x4 q0 = {qn[0], qn[1], qn[2], qn[3]};
    f32x4 q1 = {qn[4], qn[5], qn[6], qn[7]};
    f32x4 q2 = {qn[8], qn[9], qn[10], qn[11]};
    f32x4 q3 = {qn[12], qn[13], qn[14], qn[15]};
    *(f32x4*)(qp) = q0; *(f32x4*)(qp + 4) = q1;
    *(f32x4*)(qp + 8) = q2; *(f32x4*)(qp + 12) = q3;
  }
}

extern "C" void kernel_launch(void* const* d_in, const int* in_sizes, int n_in,
                              void* d_out, int out_size, void* d_ws, size_t ws_size,
                              hipStream_t stream) {
  const float* x    = (const float*)d_in[0];
  const float* hq   = (const float*)d_in[1];
  const float* qw   = (const float*)d_in[2];
  const float* rw   = (const float*)d_in[3];
  const float* tau  = (const float*)d_in[4];
  const float* syn  = (const float*)d_in[5];
  const float* corr = (const float*)d_in[6];
  unsigned short* ws = (unsigned short*)d_ws;
  unsigned short* rwfrag = ws;            // 16384 shorts
  unsigned short* qwfrag = ws + 16384;    // 4096 shorts
  unsigned short* dgfrag = ws + 20480;    // 1024 shorts
  shq_prep<<<11, 256, 0, stream>>>(qw, rw, tau, rwfrag, qwfrag, dgfrag);
  shq_main<<<B_TOTAL / NB, 512, 0, stream>>>(x, hq, syn, corr, rwfrag, qwfrag, dgfrag, (float*)d_out);
}